// Round 4
// baseline (251.355 us; speedup 1.0000x reference)
//
#include <hip/hip_runtime.h>
#include <hip/hip_bf16.h>

// ---- problem constants ----
#define B_TOT   4096
#define T_LEN   200
#define F_IN    76
#define H_DIM   128
#define S_DIM   17
#define BLK_B   16
#define NTHREADS 512
#define NT_CHUNK 8
#define NCHUNK  (T_LEN / NT_CHUNK)      // 25
#define XPITCH  104                     // shorts; 208B row = 52 dwords == 4*5 mod 32 -> 8-group bank tiling
#define HPITCH  136                     // shorts; 272B row = 68 dwords == 4   mod 32 -> 8-group bank tiling
#define ROW_F4  ((NT_CHUNK * F_IN) / 4) // 152 float4 per row per chunk
#define PF_N    5

static_assert(NCHUNK * NT_CHUNK == T_LEN, "chunking must cover T exactly");

using f32x4 = __attribute__((ext_vector_type(4))) float;
using s16x8 = __attribute__((ext_vector_type(8))) short;

#if __has_builtin(__builtin_amdgcn_exp2f)
#define EXP2(v) __builtin_amdgcn_exp2f(v)
#else
#define EXP2(v) exp2f(v)
#endif
#if __has_builtin(__builtin_amdgcn_rcpf)
#define RCP(v) __builtin_amdgcn_rcpf(v)
#else
#define RCP(v) (1.0f / (v))
#endif

__device__ __forceinline__ short f2bf(float f) {           // init-path only
    union { float f; unsigned u; } v; v.f = f;
    unsigned r = v.u + 0x7FFFu + ((v.u >> 16) & 1u);
    return (short)(r >> 16);
}
__device__ __forceinline__ float bf2f(short s) {
    union { unsigned u; float f; } v;
    v.u = ((unsigned)(unsigned short)s) << 16;
    return v.f;
}
__device__ __forceinline__ unsigned cvt_pk_bf16(float lo, float hi) {
    unsigned r;
    asm("v_cvt_pk_bf16_f32 %0, %1, %2" : "=v"(r) : "v"(lo), "v"(hi));
    return r;
}

// LDS-only barrier: do NOT drain vmcnt (keeps global prefetch in flight).
#define LDS_BARRIER() asm volatile("s_waitcnt lgkmcnt(0)\n\ts_barrier" ::: "memory")

__global__ __launch_bounds__(NTHREADS, 2) void lstm_fused(
    const float* __restrict__ x,    const float* __restrict__ stat,
    const float* __restrict__ h0,   const float* __restrict__ c0,
    const float* __restrict__ W_ih, const float* __restrict__ W_hh,
    const float* __restrict__ b_ih, const float* __restrict__ b_hh,
    const float* __restrict__ W_lin, const float* __restrict__ b_lin,
    float* __restrict__ out)
{
    __shared__ __align__(16) short xbuf[2][NT_CHUNK][BLK_B][XPITCH]; // 52 KiB
    __shared__ __align__(16) short hbuf[2][BLK_B][HPITCH];           // 8.5 KiB

    const int tid  = threadIdx.x;
    const int lane = tid & 63;
    const int wave = tid >> 6;
    const int lrow = lane & 15;          // A: M-row / B: N-col
    const int lk8  = (lane >> 4) << 3;   // k sub-base within a 32-wide K tile
    const int r0   = (lane >> 4) << 2;   // C/D batch-row base
    const int b0   = blockIdx.x * BLK_B;
    const int hb   = wave << 4;          // this wave's 16 hidden columns

    const float C1 = 1.44269504088896f;  // log2(e)
    const float gs[4] = { -C1, -C1, -2.0f * C1, -C1 }; // i,f,g,o pre-scales

    // ---- build weight B-fragments in registers (scale folded in) ----
    s16x8 wih[4][3], whh[4][4];
    f32x4 biasf[4];
#pragma unroll
    for (int nt = 0; nt < 4; ++nt) {
        const int col = nt * H_DIM + hb + lrow;   // gate row in W
        const float s = gs[nt];
#pragma unroll
        for (int kt = 0; kt < 3; ++kt) {
            s16x8 f;
#pragma unroll
            for (int j = 0; j < 8; ++j) {
                int k = kt * 32 + lk8 + j;
                float v = (k < F_IN) ? W_ih[col * F_IN + k] * s : 0.0f;
                f[j] = f2bf(v);
            }
            wih[nt][kt] = f;
        }
#pragma unroll
        for (int kt = 0; kt < 4; ++kt) {
            s16x8 f;
#pragma unroll
            for (int j = 0; j < 8; ++j) {
                int k = kt * 32 + lk8 + j;
                f[j] = f2bf(W_hh[col * H_DIM + k] * s);
            }
            whh[nt][kt] = f;
        }
        float bv = (b_ih[col] + b_hh[col]) * s;
        biasf[nt] = (f32x4){ bv, bv, bv, bv };
    }

    // ---- c0 into registers (C/D layout) ----
    float c[4];
#pragma unroll
    for (int r = 0; r < 4; ++r)
        c[r] = c0[(b0 + r0 + r) * H_DIM + hb + lrow];

    // ---- init hbuf[0] from h0; zero xbuf K-pad cols [76,XPITCH) ----
    for (int i = tid; i < BLK_B * H_DIM; i += NTHREADS) {
        int row = i >> 7, cc = i & 127;
        hbuf[0][row][cc] = f2bf(h0[(b0 + row) * H_DIM + cc]);
    }
    for (int i = tid; i < 2 * NT_CHUNK * BLK_B * (XPITCH - F_IN); i += NTHREADS) {
        int rem = i;
        int f   = rem % (XPITCH - F_IN); rem /= (XPITCH - F_IN);
        int row = rem % BLK_B;           rem /= BLK_B;
        int tt  = rem % NT_CHUNK;        rem /= NT_CHUNK;
        xbuf[rem][tt][row][F_IN + f] = 0;
    }

    // ---- staging: per-thread constants precomputed once ----
    const int prow = tid >> 5;            // 0..15 (batch row)
    const int pidx = tid & 31;            // f4 slot base within row-chunk
    const float* psrc = x + (size_t)(b0 + prow) * (T_LEN * F_IN) + pidx * 4;
    int ldsoff[PF_N];
#pragma unroll
    for (int i = 0; i < PF_N; ++i) {
        int s4 = pidx + 32 * i;           // f4 index in row-chunk
        int q  = 4 * s4;                  // float index
        int tp = (q * 863) >> 16;         // == q / 76 for q < 608
        int f0 = q - 76 * tp;
        ldsoff[i] = (tp * BLK_B + prow) * XPITCH + f0;  // short index in one buf
    }

    f32x4 pf[PF_N];
    auto issue = [&](int ch) {
        const float* p = psrc + (size_t)ch * (NT_CHUNK * F_IN);
#pragma unroll
        for (int i = 0; i < PF_N; ++i)
            if (i < PF_N - 1 || pidx < ROW_F4 - 4 * 32)   // s4 < 152
                pf[i] = *(const f32x4*)(p + i * 128);
    };
    auto commit = [&](int buf) {
        short* xb0 = &xbuf[buf][0][0][0];
#pragma unroll
        for (int i = 0; i < PF_N; ++i)
            if (i < PF_N - 1 || pidx < ROW_F4 - 4 * 32) {
                unsigned lo = cvt_pk_bf16(pf[i].x, pf[i].y);
                unsigned hi = cvt_pk_bf16(pf[i].z, pf[i].w);
                unsigned long long v = ((unsigned long long)hi << 32) | lo;
                *(unsigned long long*)(xb0 + ldsoff[i]) = v;  // 8B aligned
            }
    };

    issue(0);
    commit(0);
    __syncthreads();   // once; everything drained here is already consumed

    // ---- x-projection pipeline (ping-pong xa0/xa1, compile-time indexed) ----
    s16x8 axr[3];
    f32x4 xa0[4], xa1[4];
    auto load_ax = [&](int buf, int tt) {
#pragma unroll
        for (int kt = 0; kt < 3; ++kt)
            axr[kt] = *(const s16x8*)&xbuf[buf][tt][lrow][kt * 32 + lk8];
    };

#define REBUILD_ALL(XA)                                                          \
    {   __builtin_amdgcn_s_setprio(1);                                           \
        _Pragma("unroll")                                                        \
        for (int nt = 0; nt < 4; ++nt) {                                         \
            f32x4 t = __builtin_amdgcn_mfma_f32_16x16x32_bf16(axr[0], wih[nt][0], biasf[nt], 0, 0, 0); \
            t = __builtin_amdgcn_mfma_f32_16x16x32_bf16(axr[1], wih[nt][1], t, 0, 0, 0); \
            t = __builtin_amdgcn_mfma_f32_16x16x32_bf16(axr[2], wih[nt][2], t, 0, 0, 0); \
            XA[nt] = t;                                                          \
        }                                                                        \
        __builtin_amdgcn_s_setprio(0); }

#define LOAD_AH(CUR)                                                             \
    _Pragma("unroll")                                                            \
    for (int kt = 0; kt < 4; ++kt)                                               \
        ah[kt] = *(const s16x8*)&hbuf[CUR][lrow][kt * 32 + lk8];

#define HMFMA(XA)                                                                \
    {   __builtin_amdgcn_s_setprio(1);                                           \
        _Pragma("unroll")                                                        \
        for (int nt = 0; nt < 4; ++nt) {                                         \
            f32x4 t = __builtin_amdgcn_mfma_f32_16x16x32_bf16(ah[0], whh[nt][0], XA[nt], 0, 0, 0); \
            t = __builtin_amdgcn_mfma_f32_16x16x32_bf16(ah[1], whh[nt][1], t, 0, 0, 0); \
            t = __builtin_amdgcn_mfma_f32_16x16x32_bf16(ah[2], whh[nt][2], t, 0, 0, 0); \
            t = __builtin_amdgcn_mfma_f32_16x16x32_bf16(ah[3], whh[nt][3], t, 0, 0, 0); \
            acc[nt] = t;                                                         \
        }                                                                        \
        __builtin_amdgcn_s_setprio(0); }

#define NONLIN1(R)                                                               \
    {   float A  = EXP2(acc[0][R]);                                              \
        float Bv = EXP2(acc[1][R]);                                              \
        float E  = EXP2(acc[2][R]);                                              \
        float Dv = EXP2(acc[3][R]);                                              \
        float p1 = 1.f + A, p2 = 1.f + Bv, p3 = 1.f + E;                         \
        float q13 = p1 * p3;                                                     \
        float num = fmaf(c[R], q13, (1.f - E) * p2);                             \
        float cn  = num * RCP(q13 * p2);                                         \
        c[R] = cn;                                                               \
        float Ec  = EXP2(fminf(cn * (-2.f * C1), 80.f));                         \
        hv[R] = (1.f - Ec) * RCP((1.f + Dv) * (1.f + Ec)); }

#define NONLIN_ALL(CUR)                                                          \
    {   float hv[4];                                                             \
        NONLIN1(0); NONLIN1(1); NONLIN1(2); NONLIN1(3);                          \
        unsigned q01 = cvt_pk_bf16(hv[0], hv[1]);                                \
        unsigned q23 = cvt_pk_bf16(hv[2], hv[3]);                                \
        unsigned short* hp = (unsigned short*)&hbuf[(CUR) ^ 1][r0][hb + lrow];   \
        hp[0 * HPITCH] = (unsigned short)q01;                                    \
        hp[1 * HPITCH] = (unsigned short)(q01 >> 16);                            \
        hp[2 * HPITCH] = (unsigned short)q23;                                    \
        hp[3 * HPITCH] = (unsigned short)(q23 >> 16); }

    // prologue for chunk 0, step 0
    load_ax(0, 0);
    REBUILD_ALL(xa0)

    // Parity-staggered step: even waves [h-MFMA, nonlin, rebuild],
    // odd waves [rebuild, h-MFMA, nonlin] -> cross-wave MFMA||VALU overlap.
#define STEP(CUR, TT, XA_C, XA_N)                                                \
    {                                                                            \
        s16x8 ah[4];                                                             \
        f32x4 acc[4];                                                            \
        if (!(wave & 1)) {                                                       \
            LOAD_AH(CUR)                                                         \
            HMFMA(XA_C)                                                          \
            if ((TT) == 0 && ch + 1 < NCHUNK) issue(ch + 1);                     \
            if ((TT) < NT_CHUNK - 1) load_ax(xc, (TT) + 1);                      \
            NONLIN_ALL(CUR)                                                      \
            if ((TT) < NT_CHUNK - 1) REBUILD_ALL(XA_N)                           \
        } else {                                                                 \
            if ((TT) < NT_CHUNK - 1) { load_ax(xc, (TT) + 1); REBUILD_ALL(XA_N) } \
            LOAD_AH(CUR)                                                         \
            HMFMA(XA_C)                                                          \
            if ((TT) == 0 && ch + 1 < NCHUNK) issue(ch + 1);                     \
            NONLIN_ALL(CUR)                                                      \
        }                                                                        \
        if ((TT) == NT_CHUNK - 1 && ch + 1 < NCHUNK) commit(xc ^ 1);             \
        LDS_BARRIER();                                                           \
    }

#pragma unroll 1
    for (int ch = 0; ch < NCHUNK; ++ch) {
        const int xc = ch & 1;
        STEP(0, 0, xa0, xa1)
        STEP(1, 1, xa1, xa0)
        STEP(0, 2, xa0, xa1)
        STEP(1, 3, xa1, xa0)
        STEP(0, 4, xa0, xa1)
        STEP(1, 5, xa1, xa0)
        STEP(0, 6, xa0, xa1)
        STEP(1, 7, xa1, xa0)
        // chunk boundary: rebuild x-projection for (ch+1, tt=0) -> xa0
        if (ch + 1 < NCHUNK) {
            load_ax(xc ^ 1, 0);
            REBUILD_ALL(xa0)
        }
    }
#undef STEP
#undef NONLIN_ALL
#undef NONLIN1
#undef HMFMA
#undef LOAD_AH
#undef REBUILD_ALL

    // ---- final linear head: out[b] = [h, static] . W_lin + b_lin ----
    // 200 steps (even) -> final h is in hbuf[0]; last LDS_BARRIER ordered it.
    if (tid < BLK_B) {
        const int row = tid;
        float a = b_lin[0];
        for (int k = 0; k < H_DIM; ++k)
            a += bf2f(hbuf[0][row][k]) * W_lin[k];
        for (int s = 0; s < S_DIM; ++s)
            a += stat[(b0 + row) * S_DIM + s] * W_lin[H_DIM + s];
        out[b0 + row] = a;
    }
}

extern "C" void kernel_launch(void* const* d_in, const int* in_sizes, int n_in,
                              void* d_out, int out_size, void* d_ws, size_t ws_size,
                              hipStream_t stream) {
    const float* xx   = (const float*)d_in[0];
    const float* st   = (const float*)d_in[1];
    const float* h0   = (const float*)d_in[2];
    const float* c0   = (const float*)d_in[3];
    const float* Wih  = (const float*)d_in[4];
    const float* Whh  = (const float*)d_in[5];
    const float* bih  = (const float*)d_in[6];
    const float* bhh  = (const float*)d_in[7];
    const float* Wlin = (const float*)d_in[8];
    const float* blin = (const float*)d_in[9];
    float* o = (float*)d_out;

    lstm_fused<<<B_TOT / BLK_B, NTHREADS, 0, stream>>>(
        xx, st, h0, c0, Wih, Whh, bih, bhh, Wlin, blin, o);
}

// Round 5
// 218.193 us; speedup vs baseline: 1.1520x; 1.1520x over previous
//
#include <hip/hip_runtime.h>
#include <hip/hip_bf16.h>

// ---- problem constants ----
#define B_TOT   4096
#define T_LEN   200
#define F_IN    76
#define H_DIM   128
#define S_DIM   17
#define BLK_B   16
#define NTHREADS 512
#define NT_CHUNK 8
#define NCHUNK  (T_LEN / NT_CHUNK)      // 25
#define XPITCH  96                      // shorts; 192B row stride (16B aligned)
#define HPITCH  136                     // shorts; 272B row stride (16B aligned)
#define ROW_F4  ((NT_CHUNK * F_IN) / 4) // 152 float4 per row per chunk
#define PF_N    5

static_assert(NCHUNK * NT_CHUNK == T_LEN, "chunking must cover T exactly");

using f32x4 = __attribute__((ext_vector_type(4))) float;
using s16x8 = __attribute__((ext_vector_type(8))) short;

#if __has_builtin(__builtin_amdgcn_exp2f)
#define EXP2(v) __builtin_amdgcn_exp2f(v)
#else
#define EXP2(v) exp2f(v)
#endif
#if __has_builtin(__builtin_amdgcn_rcpf)
#define RCP(v) __builtin_amdgcn_rcpf(v)
#else
#define RCP(v) (1.0f / (v))
#endif

__device__ __forceinline__ short f2bf(float f) {           // init-path only
    union { float f; unsigned u; } v; v.f = f;
    unsigned r = v.u + 0x7FFFu + ((v.u >> 16) & 1u);
    return (short)(r >> 16);
}
__device__ __forceinline__ float bf2f(short s) {
    union { unsigned u; float f; } v;
    v.u = ((unsigned)(unsigned short)s) << 16;
    return v.f;
}
__device__ __forceinline__ unsigned cvt_pk_bf16(float lo, float hi) {
    unsigned r;
    asm("v_cvt_pk_bf16_f32 %0, %1, %2" : "=v"(r) : "v"(lo), "v"(hi));
    return r;
}

// LDS-only barrier: do NOT drain vmcnt (keeps global prefetch in flight).
#define LDS_BARRIER() asm volatile("s_waitcnt lgkmcnt(0)\n\ts_barrier" ::: "memory")

__global__ __launch_bounds__(NTHREADS, 2) void lstm_fused(
    const float* __restrict__ x,    const float* __restrict__ stat,
    const float* __restrict__ h0,   const float* __restrict__ c0,
    const float* __restrict__ W_ih, const float* __restrict__ W_hh,
    const float* __restrict__ b_ih, const float* __restrict__ b_hh,
    const float* __restrict__ W_lin, const float* __restrict__ b_lin,
    float* __restrict__ out)
{
    __shared__ __align__(16) short xbuf[2][NT_CHUNK][BLK_B][XPITCH]; // 48 KiB
    __shared__ __align__(16) short hbuf[2][BLK_B][HPITCH];           // 8.5 KiB

    const int tid  = threadIdx.x;
    const int lane = tid & 63;
    const int wave = tid >> 6;
    const int lrow = lane & 15;          // A: M-row / B: N-col
    const int lk8  = (lane >> 4) << 3;   // k sub-base within a 32-wide K tile
    const int r0   = (lane >> 4) << 2;   // C/D batch-row base
    const int b0   = blockIdx.x * BLK_B;
    const int hb   = wave << 4;          // this wave's 16 hidden columns

    const float C1 = 1.44269504088896f;  // log2(e)
    const float gs[4] = { -C1, -C1, -2.0f * C1, -C1 }; // i,f,g,o pre-scales

    // ---- build weight B-fragments in registers (scale folded in) ----
    s16x8 wih[4][3], whh[4][4];
    f32x4 biasf[4];
#pragma unroll
    for (int nt = 0; nt < 4; ++nt) {
        const int col = nt * H_DIM + hb + lrow;   // gate row in W
        const float s = gs[nt];
#pragma unroll
        for (int kt = 0; kt < 3; ++kt) {
            s16x8 f;
#pragma unroll
            for (int j = 0; j < 8; ++j) {
                int k = kt * 32 + lk8 + j;
                float v = (k < F_IN) ? W_ih[col * F_IN + k] * s : 0.0f;
                f[j] = f2bf(v);
            }
            wih[nt][kt] = f;
        }
#pragma unroll
        for (int kt = 0; kt < 4; ++kt) {
            s16x8 f;
#pragma unroll
            for (int j = 0; j < 8; ++j) {
                int k = kt * 32 + lk8 + j;
                f[j] = f2bf(W_hh[col * H_DIM + k] * s);
            }
            whh[nt][kt] = f;
        }
        float bv = (b_ih[col] + b_hh[col]) * s;
        biasf[nt] = (f32x4){ bv, bv, bv, bv };
    }

    // ---- c0 into registers (C/D layout) ----
    float c[4];
#pragma unroll
    for (int r = 0; r < 4; ++r)
        c[r] = c0[(b0 + r0 + r) * H_DIM + hb + lrow];

    // ---- init hbuf[0] from h0; zero xbuf K-pad cols [76,96) ----
    for (int i = tid; i < BLK_B * H_DIM; i += NTHREADS) {
        int row = i >> 7, cc = i & 127;
        hbuf[0][row][cc] = f2bf(h0[(b0 + row) * H_DIM + cc]);
    }
    for (int i = tid; i < 2 * NT_CHUNK * BLK_B * (XPITCH - F_IN); i += NTHREADS) {
        int rem = i;
        int f   = rem % (XPITCH - F_IN); rem /= (XPITCH - F_IN);
        int row = rem % BLK_B;           rem /= BLK_B;
        int tt  = rem % NT_CHUNK;        rem /= NT_CHUNK;
        xbuf[rem][tt][row][F_IN + f] = 0;
    }

    // ---- staging: per-thread constants precomputed once ----
    const int prow = tid >> 5;            // 0..15 (batch row)
    const int pidx = tid & 31;            // f4 slot base within row-chunk
    const float* psrc = x + (size_t)(b0 + prow) * (T_LEN * F_IN) + pidx * 4;
    int ldsoff[PF_N];
#pragma unroll
    for (int i = 0; i < PF_N; ++i) {
        int s4 = pidx + 32 * i;           // f4 index in row-chunk
        int q  = 4 * s4;                  // float index
        int tp = (q * 863) >> 16;         // == q / 76 for q < 608
        int f0 = q - 76 * tp;
        ldsoff[i] = (tp * BLK_B + prow) * XPITCH + f0;  // short index in one buf
    }

    f32x4 pf[PF_N];
    auto issue = [&](int ch) {
        const float* p = psrc + (size_t)ch * (NT_CHUNK * F_IN);
#pragma unroll
        for (int i = 0; i < PF_N; ++i)
            if (i < PF_N - 1 || pidx < ROW_F4 - 4 * 32)   // s4 < 152
                pf[i] = *(const f32x4*)(p + i * 128);
    };
    auto commit = [&](int buf) {
        short* xb0 = &xbuf[buf][0][0][0];
#pragma unroll
        for (int i = 0; i < PF_N; ++i)
            if (i < PF_N - 1 || pidx < ROW_F4 - 4 * 32) {
                unsigned lo = cvt_pk_bf16(pf[i].x, pf[i].y);
                unsigned hi = cvt_pk_bf16(pf[i].z, pf[i].w);
                unsigned long long v = ((unsigned long long)hi << 32) | lo;
                *(unsigned long long*)(xb0 + ldsoff[i]) = v;  // 8B aligned
            }
    };

    issue(0);
    commit(0);
    __syncthreads();   // once; everything drained here is already consumed

    // ---- static wave priority: even waves preferred by the issue arbiter.
    // After each barrier both waves race into the MFMA cluster; the even wave
    // wins the matrix pipe, finishes first, and enters the VALU (nonlin) phase
    // while the odd wave's MFMAs drain -> cross-wave MFMA||VALU overlap with
    // identical code on both waves (no I$ growth, no divergence).
    if (!(wave & 1)) __builtin_amdgcn_s_setprio(1);

    // ---- x-projection pipeline ----
    s16x8 axr[3];
    f32x4 xa[4];
    auto load_ax = [&](int buf, int tt) {
#pragma unroll
        for (int kt = 0; kt < 3; ++kt)
            axr[kt] = *(const s16x8*)&xbuf[buf][tt][lrow][kt * 32 + lk8];
    };

#define REBUILD(NT)                                                              \
    xa[NT] = __builtin_amdgcn_mfma_f32_16x16x32_bf16(axr[2], wih[NT][2],         \
             __builtin_amdgcn_mfma_f32_16x16x32_bf16(axr[1], wih[NT][1],         \
             __builtin_amdgcn_mfma_f32_16x16x32_bf16(axr[0], wih[NT][0],         \
             biasf[NT], 0, 0, 0), 0, 0, 0), 0, 0, 0)

#define NONLIN(R)                                                                \
    {   float A  = EXP2(acc[0][R]);                                              \
        float Bv = EXP2(acc[1][R]);                                              \
        float E  = EXP2(acc[2][R]);                                              \
        float Dv = EXP2(acc[3][R]);                                              \
        float p1 = 1.f + A, p2 = 1.f + Bv, p3 = 1.f + E;                         \
        float q13 = p1 * p3;                                                     \
        float num = fmaf(c[R], q13, (1.f - E) * p2);                             \
        float cn  = num * RCP(q13 * p2);                                         \
        c[R] = cn;                                                               \
        float Ec  = EXP2(fminf(cn * (-2.f * C1), 80.f));                         \
        hv[R] = (1.f - Ec) * RCP((1.f + Dv) * (1.f + Ec)); }

    // prologue for chunk 0, step 0
    load_ax(0, 0);
    REBUILD(0); REBUILD(1); REBUILD(2); REBUILD(3);

#define STEP(CUR, TT)                                                            \
    {                                                                            \
        s16x8 ah[4];                                                             \
        _Pragma("unroll")                                                        \
        for (int kt = 0; kt < 4; ++kt)                                           \
            ah[kt] = *(const s16x8*)&hbuf[CUR][lrow][kt * 32 + lk8];             \
        if ((TT) < NT_CHUNK - 1) load_ax(xc, (TT) + 1);                          \
        f32x4 acc[4];                                                            \
        _Pragma("unroll")                                                        \
        for (int nt = 0; nt < 4; ++nt) {                                         \
            f32x4 t = __builtin_amdgcn_mfma_f32_16x16x32_bf16(ah[0], whh[nt][0], xa[nt], 0, 0, 0); \
            t = __builtin_amdgcn_mfma_f32_16x16x32_bf16(ah[1], whh[nt][1], t, 0, 0, 0); \
            t = __builtin_amdgcn_mfma_f32_16x16x32_bf16(ah[2], whh[nt][2], t, 0, 0, 0); \
            t = __builtin_amdgcn_mfma_f32_16x16x32_bf16(ah[3], whh[nt][3], t, 0, 0, 0); \
            acc[nt] = t;                                                         \
        }                                                                        \
        if ((TT) == 0 && ch + 1 < NCHUNK) issue(ch + 1);                         \
        float hv[4];                                                             \
        unsigned short* hp = (unsigned short*)&hbuf[(CUR) ^ 1][r0][hb + lrow];   \
        NONLIN(0);                                                               \
        if ((TT) < NT_CHUNK - 1) { REBUILD(0); }                                 \
        NONLIN(1);                                                               \
        {   unsigned q01 = cvt_pk_bf16(hv[0], hv[1]);                            \
            hp[0 * HPITCH] = (unsigned short)q01;                                \
            hp[1 * HPITCH] = (unsigned short)(q01 >> 16); }                      \
        if ((TT) < NT_CHUNK - 1) { REBUILD(1); }                                 \
        NONLIN(2);                                                               \
        if ((TT) < NT_CHUNK - 1) { REBUILD(2); }                                 \
        NONLIN(3);                                                               \
        {   unsigned q23 = cvt_pk_bf16(hv[2], hv[3]);                            \
            hp[2 * HPITCH] = (unsigned short)q23;                                \
            hp[3 * HPITCH] = (unsigned short)(q23 >> 16); }                      \
        if ((TT) < NT_CHUNK - 1) { REBUILD(3); }                                 \
        if ((TT) == NT_CHUNK - 1 && ch + 1 < NCHUNK) commit(xc ^ 1);             \
        LDS_BARRIER();                                                           \
    }

#pragma unroll 1
    for (int ch = 0; ch < NCHUNK; ++ch) {
        const int xc = ch & 1;
        STEP(0, 0)
        STEP(1, 1)
        STEP(0, 2)
        STEP(1, 3)
        STEP(0, 4)
        STEP(1, 5)
        STEP(0, 6)
        STEP(1, 7)
        // chunk boundary: rebuild x-projection for (ch+1, tt=0) from fresh buffer
        if (ch + 1 < NCHUNK) {
            load_ax(xc ^ 1, 0);
            REBUILD(0); REBUILD(1); REBUILD(2); REBUILD(3);
        }
    }
#undef STEP
#undef NONLIN
#undef REBUILD

    // ---- final linear head: out[b] = [h, static] . W_lin + b_lin ----
    // 200 steps (even) -> final h is in hbuf[0]; last LDS_BARRIER ordered it.
    if (tid < BLK_B) {
        const int row = tid;
        float a = b_lin[0];
        for (int k = 0; k < H_DIM; ++k)
            a += bf2f(hbuf[0][row][k]) * W_lin[k];
        for (int s = 0; s < S_DIM; ++s)
            a += stat[(b0 + row) * S_DIM + s] * W_lin[H_DIM + s];
        out[b0 + row] = a;
    }
}

extern "C" void kernel_launch(void* const* d_in, const int* in_sizes, int n_in,
                              void* d_out, int out_size, void* d_ws, size_t ws_size,
                              hipStream_t stream) {
    const float* xx   = (const float*)d_in[0];
    const float* st   = (const float*)d_in[1];
    const float* h0   = (const float*)d_in[2];
    const float* c0   = (const float*)d_in[3];
    const float* Wih  = (const float*)d_in[4];
    const float* Whh  = (const float*)d_in[5];
    const float* bih  = (const float*)d_in[6];
    const float* bhh  = (const float*)d_in[7];
    const float* Wlin = (const float*)d_in[8];
    const float* blin = (const float*)d_in[9];
    float* o = (float*)d_out;

    lstm_fused<<<B_TOT / BLK_B, NTHREADS, 0, stream>>>(
        xx, st, h0, c0, Wih, Whh, bih, bhh, Wlin, blin, o);
}

// Round 6
// 204.536 us; speedup vs baseline: 1.2289x; 1.0668x over previous
//
#include <hip/hip_runtime.h>
#include <hip/hip_bf16.h>

// ---- problem constants ----
#define B_TOT   4096
#define T_LEN   200
#define F_IN    76
#define H_DIM   128
#define S_DIM   17
#define BLK_B   16
#define NTHREADS 512
#define NT_CHUNK 8
#define NCHUNK  (T_LEN / NT_CHUNK)      // 25
#define XPITCH  104                     // shorts; 208B row = 52 dwords == 20 mod 32 -> 8 bank-groups, 2-way (free)
#define HPITCH  136                     // shorts; 272B row = 68 dwords == 4 mod 32  -> 8 bank-groups, 2-way (free)
#define ROW_F4  ((NT_CHUNK * F_IN) / 4) // 152 float4 per row per chunk
#define PF_N    5

static_assert(NCHUNK * NT_CHUNK == T_LEN, "chunking must cover T exactly");

using f32x4 = __attribute__((ext_vector_type(4))) float;
using s16x8 = __attribute__((ext_vector_type(8))) short;

#if __has_builtin(__builtin_amdgcn_exp2f)
#define EXP2(v) __builtin_amdgcn_exp2f(v)
#else
#define EXP2(v) exp2f(v)
#endif
#if __has_builtin(__builtin_amdgcn_rcpf)
#define RCP(v) __builtin_amdgcn_rcpf(v)
#else
#define RCP(v) (1.0f / (v))
#endif

__device__ __forceinline__ short f2bf(float f) {           // init-path only
    union { float f; unsigned u; } v; v.f = f;
    unsigned r = v.u + 0x7FFFu + ((v.u >> 16) & 1u);
    return (short)(r >> 16);
}
__device__ __forceinline__ float bf2f(short s) {
    union { unsigned u; float f; } v;
    v.u = ((unsigned)(unsigned short)s) << 16;
    return v.f;
}
__device__ __forceinline__ unsigned cvt_pk_bf16(float lo, float hi) {
    unsigned r;
    asm("v_cvt_pk_bf16_f32 %0, %1, %2" : "=v"(r) : "v"(lo), "v"(hi));
    return r;
}

// LDS-only barrier: do NOT drain vmcnt (keeps global prefetch in flight).
#define LDS_BARRIER() asm volatile("s_waitcnt lgkmcnt(0)\n\ts_barrier" ::: "memory")

__global__ __launch_bounds__(NTHREADS, 2) void lstm_fused(
    const float* __restrict__ x,    const float* __restrict__ stat,
    const float* __restrict__ h0,   const float* __restrict__ c0,
    const float* __restrict__ W_ih, const float* __restrict__ W_hh,
    const float* __restrict__ b_ih, const float* __restrict__ b_hh,
    const float* __restrict__ W_lin, const float* __restrict__ b_lin,
    float* __restrict__ out)
{
    __shared__ __align__(16) short xbuf[2][NT_CHUNK][BLK_B][XPITCH]; // 52 KiB
    __shared__ __align__(16) short hbuf[2][BLK_B][HPITCH];           // 8.5 KiB

    const int tid  = threadIdx.x;
    const int lane = tid & 63;
    const int wave = tid >> 6;
    const int lrow = lane & 15;          // A: M-row / B: N-col
    const int lk8  = (lane >> 4) << 3;   // k sub-base within a 32-wide K tile
    const int r0   = (lane >> 4) << 2;   // C/D batch-row base
    const int b0   = blockIdx.x * BLK_B;
    const int hb   = wave << 4;          // this wave's 16 hidden columns

    const float C1 = 1.44269504088896f;  // log2(e)
    const float gs[4] = { -C1, -C1, -2.0f * C1, -C1 }; // i,f,g,o pre-scales

    // ---- build weight B-fragments in registers (scale folded in) ----
    s16x8 wih[4][3], whh[4][4];
    f32x4 biasf[4];
#pragma unroll
    for (int nt = 0; nt < 4; ++nt) {
        const int col = nt * H_DIM + hb + lrow;   // gate row in W
        const float s = gs[nt];
#pragma unroll
        for (int kt = 0; kt < 3; ++kt) {
            s16x8 f;
#pragma unroll
            for (int j = 0; j < 8; ++j) {
                int k = kt * 32 + lk8 + j;
                float v = (k < F_IN) ? W_ih[col * F_IN + k] * s : 0.0f;
                f[j] = f2bf(v);
            }
            wih[nt][kt] = f;
        }
#pragma unroll
        for (int kt = 0; kt < 4; ++kt) {
            s16x8 f;
#pragma unroll
            for (int j = 0; j < 8; ++j) {
                int k = kt * 32 + lk8 + j;
                f[j] = f2bf(W_hh[col * H_DIM + k] * s);
            }
            whh[nt][kt] = f;
        }
        float bv = (b_ih[col] + b_hh[col]) * s;
        biasf[nt] = (f32x4){ bv, bv, bv, bv };
    }

    // ---- c0 into registers (C/D layout) ----
    float c[4];
#pragma unroll
    for (int r = 0; r < 4; ++r)
        c[r] = c0[(b0 + r0 + r) * H_DIM + hb + lrow];

    // ---- init hbuf[0] from h0; zero xbuf K-pad cols [76,XPITCH) ----
    for (int i = tid; i < BLK_B * H_DIM; i += NTHREADS) {
        int row = i >> 7, cc = i & 127;
        hbuf[0][row][cc] = f2bf(h0[(b0 + row) * H_DIM + cc]);
    }
    for (int i = tid; i < 2 * NT_CHUNK * BLK_B * (XPITCH - F_IN); i += NTHREADS) {
        int rem = i;
        int f   = rem % (XPITCH - F_IN); rem /= (XPITCH - F_IN);
        int row = rem % BLK_B;           rem /= BLK_B;
        int tt  = rem % NT_CHUNK;        rem /= NT_CHUNK;
        xbuf[rem][tt][row][F_IN + f] = 0;
    }

    // ---- staging: per-thread constants precomputed once ----
    const int prow = tid >> 5;            // 0..15 (batch row)
    const int pidx = tid & 31;            // f4 slot base within row-chunk
    const float* psrc = x + (size_t)(b0 + prow) * (T_LEN * F_IN) + pidx * 4;
    int ldsoff[PF_N];
#pragma unroll
    for (int i = 0; i < PF_N; ++i) {
        int s4 = pidx + 32 * i;           // f4 index in row-chunk
        int q  = 4 * s4;                  // float index
        int tp = (q * 863) >> 16;         // == q / 76 for q < 608
        int f0 = q - 76 * tp;
        ldsoff[i] = (tp * BLK_B + prow) * XPITCH + f0;  // short index in one buf
    }

    f32x4 pf[PF_N];
    auto issue = [&](int ch) {
        const float* p = psrc + (size_t)ch * (NT_CHUNK * F_IN);
#pragma unroll
        for (int i = 0; i < PF_N; ++i)
            if (i < PF_N - 1 || pidx < ROW_F4 - 4 * 32)   // s4 < 152
                pf[i] = *(const f32x4*)(p + i * 128);
    };
    auto commit = [&](int buf) {
        short* xb0 = &xbuf[buf][0][0][0];
#pragma unroll
        for (int i = 0; i < PF_N; ++i)
            if (i < PF_N - 1 || pidx < ROW_F4 - 4 * 32) {
                unsigned lo = cvt_pk_bf16(pf[i].x, pf[i].y);
                unsigned hi = cvt_pk_bf16(pf[i].z, pf[i].w);
                unsigned long long v = ((unsigned long long)hi << 32) | lo;
                *(unsigned long long*)(xb0 + ldsoff[i]) = v;  // 8B aligned
            }
    };

    issue(0);
    commit(0);
    __syncthreads();   // once; everything drained here is already consumed

    // ---- x-projection pipeline ----
    s16x8 axr[3];
    f32x4 xa[4];
    auto load_ax = [&](int buf, int tt) {
#pragma unroll
        for (int kt = 0; kt < 3; ++kt)
            axr[kt] = *(const s16x8*)&xbuf[buf][tt][lrow][kt * 32 + lk8];
    };

#define REBUILD(NT)                                                              \
    xa[NT] = __builtin_amdgcn_mfma_f32_16x16x32_bf16(axr[2], wih[NT][2],         \
             __builtin_amdgcn_mfma_f32_16x16x32_bf16(axr[1], wih[NT][1],         \
             __builtin_amdgcn_mfma_f32_16x16x32_bf16(axr[0], wih[NT][0],         \
             biasf[NT], 0, 0, 0), 0, 0, 0), 0, 0, 0)

#define COMBINE(R)                                                               \
    {   float p1 = 1.f + e0[R], p2 = 1.f + e1[R], p3 = 1.f + e2[R];              \
        float q13 = p1 * p3;                                                     \
        float num = fmaf(c[R], q13, (1.f - e2[R]) * p2);                         \
        float cn  = num * RCP(q13 * p2);                                         \
        c[R] = cn;                                                               \
        float Ec  = EXP2(fminf(cn * (-2.f * C1), 80.f));                         \
        hv[R] = (1.f - Ec) * RCP((1.f + e3[R]) * (1.f + Ec)); }

    // prologue for chunk 0, step 0
    load_ax(0, 0);
    REBUILD(0); REBUILD(1); REBUILD(2); REBUILD(3);

    // Step order (post-barrier): ah reads first (critical), ax(t+1) reads queued
    // behind them; h-MFMA chains start at lgkmcnt(3); the 16 early per-gate exp2
    // start as each gate chain completes; the 12 REBUILD MFMAs then fill the
    // matrix pipe while the trans ops drain; cheap per-row combine last.
#define STEP(CUR, TT)                                                            \
    {                                                                            \
        s16x8 ah[4];                                                             \
        _Pragma("unroll")                                                        \
        for (int kt = 0; kt < 4; ++kt)                                           \
            ah[kt] = *(const s16x8*)&hbuf[CUR][lrow][kt * 32 + lk8];             \
        if ((TT) < NT_CHUNK - 1) load_ax(xc, (TT) + 1);                          \
        f32x4 acc[4];                                                            \
        _Pragma("unroll")                                                        \
        for (int nt = 0; nt < 4; ++nt) {                                         \
            f32x4 t = __builtin_amdgcn_mfma_f32_16x16x32_bf16(ah[0], whh[nt][0], xa[nt], 0, 0, 0); \
            t = __builtin_amdgcn_mfma_f32_16x16x32_bf16(ah[1], whh[nt][1], t, 0, 0, 0); \
            t = __builtin_amdgcn_mfma_f32_16x16x32_bf16(ah[2], whh[nt][2], t, 0, 0, 0); \
            t = __builtin_amdgcn_mfma_f32_16x16x32_bf16(ah[3], whh[nt][3], t, 0, 0, 0); \
            acc[nt] = t;                                                         \
        }                                                                        \
        if ((TT) == 0 && ch + 1 < NCHUNK) issue(ch + 1);                         \
        float e0[4], e1[4], e2[4], e3[4];                                        \
        _Pragma("unroll")                                                        \
        for (int r = 0; r < 4; ++r) e0[r] = EXP2(acc[0][r]);                     \
        _Pragma("unroll")                                                        \
        for (int r = 0; r < 4; ++r) e1[r] = EXP2(acc[1][r]);                     \
        _Pragma("unroll")                                                        \
        for (int r = 0; r < 4; ++r) e2[r] = EXP2(acc[2][r]);                     \
        _Pragma("unroll")                                                        \
        for (int r = 0; r < 4; ++r) e3[r] = EXP2(acc[3][r]);                     \
        if ((TT) < NT_CHUNK - 1) { REBUILD(0); REBUILD(1); REBUILD(2); REBUILD(3); } \
        float hv[4];                                                             \
        unsigned short* hp = (unsigned short*)&hbuf[(CUR) ^ 1][r0][hb + lrow];   \
        COMBINE(0); COMBINE(1);                                                  \
        {   unsigned q01 = cvt_pk_bf16(hv[0], hv[1]);                            \
            hp[0 * HPITCH] = (unsigned short)q01;                                \
            hp[1 * HPITCH] = (unsigned short)(q01 >> 16); }                      \
        COMBINE(2); COMBINE(3);                                                  \
        {   unsigned q23 = cvt_pk_bf16(hv[2], hv[3]);                            \
            hp[2 * HPITCH] = (unsigned short)q23;                                \
            hp[3 * HPITCH] = (unsigned short)(q23 >> 16); }                      \
        if ((TT) == NT_CHUNK - 1 && ch + 1 < NCHUNK) commit(xc ^ 1);             \
        LDS_BARRIER();                                                           \
    }

#pragma unroll 1
    for (int ch = 0; ch < NCHUNK; ++ch) {
        const int xc = ch & 1;
        STEP(0, 0)
        STEP(1, 1)
        STEP(0, 2)
        STEP(1, 3)
        STEP(0, 4)
        STEP(1, 5)
        STEP(0, 6)
        STEP(1, 7)
        // chunk boundary: rebuild x-projection for (ch+1, tt=0) from fresh buffer
        // (must be post-barrier: commit was done by other threads this step)
        if (ch + 1 < NCHUNK) {
            load_ax(xc ^ 1, 0);
            REBUILD(0); REBUILD(1); REBUILD(2); REBUILD(3);
        }
    }
#undef STEP
#undef COMBINE
#undef REBUILD

    // ---- final linear head: out[b] = [h, static] . W_lin + b_lin ----
    // 200 steps (even) -> final h is in hbuf[0]; last LDS_BARRIER ordered it.
    if (tid < BLK_B) {
        const int row = tid;
        float a = b_lin[0];
        for (int k = 0; k < H_DIM; ++k)
            a += bf2f(hbuf[0][row][k]) * W_lin[k];
        for (int s = 0; s < S_DIM; ++s)
            a += stat[(b0 + row) * S_DIM + s] * W_lin[H_DIM + s];
        out[b0 + row] = a;
    }
}

extern "C" void kernel_launch(void* const* d_in, const int* in_sizes, int n_in,
                              void* d_out, int out_size, void* d_ws, size_t ws_size,
                              hipStream_t stream) {
    const float* xx   = (const float*)d_in[0];
    const float* st   = (const float*)d_in[1];
    const float* h0   = (const float*)d_in[2];
    const float* c0   = (const float*)d_in[3];
    const float* Wih  = (const float*)d_in[4];
    const float* Whh  = (const float*)d_in[5];
    const float* bih  = (const float*)d_in[6];
    const float* bhh  = (const float*)d_in[7];
    const float* Wlin = (const float*)d_in[8];
    const float* blin = (const float*)d_in[9];
    float* o = (float*)d_out;

    lstm_fused<<<B_TOT / BLK_B, NTHREADS, 0, stream>>>(
        xx, st, h0, c0, Wih, Whh, bih, bhh, Wlin, blin, o);
}